// Round 19
// baseline (266.199 us; speedup 1.0000x reference)
//
#include <hip/hip_runtime.h>
#include <math.h>

#define ZDIM  128
#define ODIM  16
#define INDIM 274
#define TJ    32
#define GCOEFF (-2016.125f)
#define DMAX  2.25f
#define GDELTA (2.0f / 127.0f)

// workspace layout (float offsets)
#define OFF_TABP  0        // 128*8  {sg1,sg2,sb1,sb2,w144_1,w144_2,0,0}
#define OFF_FDOP  1024     // 4*128*2 paired
#define OFF_W3HI  2048     // 2048 ushort = 1024 floats (W3 B-frag order, hi)
#define OFF_W3LO  3072     // 1024 floats (lo)
#define OFF_FDSUM 4096     // 4
#define OFF_FDSQ  4100     // 4
#define OFF_RR    4104     // 4*N*3 = 4608
#define OFF_BHI   8720     // 32768 ushort (rpe-GEMM B frags hi)
#define OFF_BLO   25104    // 32768 ushort
#define OFF_CWGP  41488    // 128*256 fp32 paired cols [g][2q|2q+1]

#define RSTRIDE 264        // s_rdotb row stride in ushorts (16B-aligned rows)

// s_tab4 de-swizzle: float index 4q + 4*(q>>3) (r13-validated).
#define T4IDX(q) (4 * (q) + 4 * ((q) >> 3))

typedef __attribute__((ext_vector_type(8))) short bf16x8;
typedef __attribute__((ext_vector_type(4))) float f32x4;
#define MFMA_BF16 __builtin_amdgcn_mfma_f32_16x16x32_bf16

static __device__ inline ushort f2bf(float x) {
  union { float f; unsigned u; } v; v.f = x;
  unsigned r = v.u + 0x7fffu + ((v.u >> 16) & 1u);
  return (ushort)(r >> 16);
}
static __device__ inline float bf2f(ushort h) {
  union { unsigned u; float f; } v; v.u = ((unsigned)h) << 16;
  return v.f;
}
// SCRATCH-SPILL CATALOG: (a) local arrays w/ runtime index (r10); (b)
// address-taking of locals (r7); (c) ext-vector element inserts even with
// literal index (r15); (d) plain register PRESSURE from too much fused live
// state (r17). Clean: named scalars, bit-ops, make_uint4 + bit_cast.
static __device__ inline unsigned pk2(float a, float b) {
  ushort ua = __builtin_bit_cast(ushort, (__bf16)a);
  ushort ub = __builtin_bit_cast(ushort, (__bf16)b);
  return (unsigned)ua | ((unsigned)ub << 16);
}
static __device__ inline bf16x8 cvt8h(float4 a, float4 b) {
  return __builtin_bit_cast(
      bf16x8, make_uint4(pk2(a.x, a.y), pk2(a.z, a.w),
                         pk2(b.x, b.y), pk2(b.z, b.w)));
}

// Fused preprocessing (unchanged):
__global__ __launch_bounds__(256) void k0_all(
    const float* __restrict__ nf, const float* __restrict__ Wf,
    const float* __restrict__ gamma, const float* __restrict__ beta,
    const float* __restrict__ W1, const float* __restrict__ W2,
    const float* __restrict__ W3, const float* __restrict__ ttra,
    const float* __restrict__ rn, float* __restrict__ ws, int N, int A) {
  const int blk = blockIdx.x;
  const int t = threadIdx.x;

  if (blk < 264) {
    const int flat = blk * 256 + t;
    if (flat < 32768) {
      int e = flat & 7, l = (flat >> 3) & 63, ct = (flat >> 9) & 15, kt = flat >> 13;
      int z = kt * 32 + (l >> 4) * 8 + e;
      int n = ct * 16 + (l & 15);
      int q = n >> 1;
      const float* row = (n & 1) ? (W2 + (size_t)q * INDIM) : (W1 + (size_t)q * INDIM);
      float v = gamma[146 + z] * row[146 + z];
      ushort h = f2bf(v);
      ushort lo = f2bf(v - bf2f(h));
      ((ushort*)(ws + OFF_BHI))[flat] = h;
      ((ushort*)(ws + OFF_BLO))[flat] = lo;
    } else if (flat < 65536) {
      int c = flat - 32768;
      int g = c >> 8, n = c & 255, q = n >> 1;
      const float* row = (n & 1) ? (W2 + (size_t)q * INDIM) : (W1 + (size_t)q * INDIM);
      ws[OFF_CWGP + g * 256 + n] = gamma[16 + g] * row[16 + g];
    } else if (flat < 67584) {
      int f = flat - 65536;  // 0..2047
      int e = f & 7, l = (f >> 3) & 63, kt = (f >> 9) & 3;
      int o = l & 15;
      int q = kt * 32 + (l >> 4) * 8 + e;
      float v = W3[o * 128 + q];
      ushort h = f2bf(v);
      ushort lo = f2bf(v - bf2f(h));
      ((ushort*)(ws + OFF_W3HI))[f] = h;
      ((ushort*)(ws + OFF_W3LO))[f] = lo;
    }
    return;
  }

  if (blk == 264) {
    __shared__ float fd[64];
    if (t < 64) {
      int bm = t >> 4, c = t & 15;
      const float4* a4 = (const float4*)(nf + bm * 256);
      const float4* b4 = (const float4*)(Wf + c * 256);
      float s = 0.f;
      for (int f = 0; f < 64; ++f) {
        float4 a = a4[f], b = b4[f];
        s += a.x * b.x + a.y * b.y + a.z * b.z + a.w * b.w;
      }
      fd[t] = s;
    }
    __syncthreads();
    {
      int q = t & 127, which = t >> 7;
      const float* r = which ? (W2 + (size_t)q * INDIM) : (W1 + (size_t)q * INDIM);
      float sg = 0.f, sb = 0.f;
      for (int c = 0; c < INDIM; ++c) { sg += gamma[c] * r[c]; sb += beta[c] * r[c]; }
      float* tp = ws + OFF_TABP + q * 8;
      tp[0 + which] = sg;
      tp[2 + which] = sb;
      tp[4 + which] = gamma[144] * r[144];
      if (!which) { tp[6] = 0.f; tp[7] = 0.f; }
      for (int bm = 0; bm < 4; ++bm) {
        float f1 = 0.f;
        for (int c = 0; c < 16; ++c) f1 += fd[bm * 16 + c] * gamma[c] * r[c];
        ws[OFF_FDOP + (bm * 128 + q) * 2 + which] = f1;
      }
    }
    if (t < 4) {
      float s = 0.f, q = 0.f;
      for (int c = 0; c < 16; ++c) { float v = fd[t * 16 + c]; s += v; q += v * v; }
      ws[OFF_FDSUM + t] = s;
      ws[OFF_FDSQ + t] = q;
    }
    return;
  }

  // r_repr
  {
    int w = t >> 6, lane = t & 63;
    int flat = (blk - 265) * 4 + w;
    if (flat >= 4 * N) return;
    int bm = flat / N, n = flat - bm * N;
    float a0 = 0.f, a1 = 0.f, a2 = 0.f;
    for (int a = lane; a < A; a += 64) {
      float wv = ttra[(size_t)n * A + a];
      const float* rp = rn + ((size_t)bm * A + a) * 3;
      a0 += wv * rp[0]; a1 += wv * rp[1]; a2 += wv * rp[2];
    }
    for (int s = 32; s; s >>= 1) {
      a0 += __shfl_down(a0, s); a1 += __shfl_down(a1, s); a2 += __shfl_down(a2, s);
    }
    if (lane == 0) {
      float* o = ws + OFF_RR + ((size_t)bm * N + n) * 3;
      o[0] = a0; o[1] = a1; o[2] = a2;
    }
  }
}

// k2: MFMA rdot GEMM (2-product) + MFMA xW3 epilogue (2-product), r18
// structure (direct C-frag stores). Round-19: __launch_bounds__(256,6) —
// latency-bound at 4 blocks/CU (occ 36.8%, no pipe >41%); LDS 25088 B allows
// 6 blocks/CU and VGPR cap 512/6=85 >= current 64, so raise residency to
// hide the VALU/LDS dependency chains.
__global__ __launch_bounds__(256, 6) void k2_main(
    const float* __restrict__ rpe, const float* __restrict__ ws,
    float* __restrict__ out, int N) {
  const int t = threadIdx.x;
  const int njt = N / TJ;
  const int i = blockIdx.x / njt;
  const int j0 = (blockIdx.x % njt) * TJ;

  __shared__ ushort s_rdotb[32 * RSTRIDE];  // 16896 B
  __shared__ float s_tab4s[T4IDX(127) + 4]; // de-swizzled {sg1,sg2,sb1,sb2}
  __shared__ float2 s_tabw[128];            // {w144_1,w144_2}
  __shared__ float s_fdop[1024];            // [bm*256 + 2q + which]
  __shared__ float s_rsum[32], s_rsq[32];
  __shared__ float s_d[128];

  // --- stage tables (read only after the post-GEMM barrier) ---
  if (t < 128) {
    *(float4*)(s_tab4s + T4IDX(t)) = *(const float4*)(ws + OFF_TABP + t * 8);
    s_tabw[t] = *(const float2*)(ws + OFF_TABP + t * 8 + 4);
  }
  for (int idx = t; idx < 1024; idx += 256) s_fdop[idx] = ws[OFF_FDOP + idx];

  // --- distances ---
  if (t < 128) {
    int bm = t >> 5, p = t & 31;
    const float* rr = ws + OFF_RR;
    const float* ri = rr + ((size_t)bm * N + i) * 3;
    const float* rj = rr + ((size_t)bm * N + j0 + p) * 3;
    float dx = ri[0] - rj[0], dy = ri[1] - rj[1], dz = ri[2] - rj[2];
    float sq = dx * dx + dy * dy + dz * dz;
    s_d[t] = sq > 0.f ? sqrtf(sq) : 0.f;
  }
  // --- rpe row sums (4 threads per row) ---
  if (t < 128) {
    int p = t >> 2, seg = t & 3;
    const float* row = rpe + ((size_t)(i * N) + j0 + p) * ZDIM + seg * 32;
    float s = 0.f, q = 0.f;
    for (int u = 0; u < 32; u += 4) {
      float4 v = *(const float4*)(row + u);
      s += v.x + v.y + v.z + v.w;
      q += v.x * v.x + v.y * v.y + v.z * v.z + v.w * v.w;
    }
    s += __shfl_xor(s, 1); q += __shfl_xor(q, 1);
    s += __shfl_xor(s, 2); q += __shfl_xor(q, 2);
    if (seg == 0) { s_rsum[p] = s; s_rsq[p] = q; }
  }

  // --- MFMA GEMM: rdot[32 rows][256 paired cols], 2-product split ---
  {
    const int w = t >> 6, l = t & 63, lm = l & 15, lk = l >> 4;
    f32x4 acc[2][4];
#pragma unroll
    for (int mt = 0; mt < 2; ++mt)
#pragma unroll
      for (int nt = 0; nt < 4; ++nt) acc[mt][nt] = (f32x4){0.f, 0.f, 0.f, 0.f};
    const float* a0p = rpe + ((size_t)(i * N) + j0 + lm) * ZDIM;
    const float* a1p = a0p + 16 * ZDIM;
    const ushort* bhip = (const ushort*)(ws + OFF_BHI);
    const ushort* blop = (const ushort*)(ws + OFF_BLO);
#pragma unroll
    for (int kt = 0; kt < 4; ++kt) {
      const int ko = kt * 32 + lk * 8;
      bf16x8 ah0 = cvt8h(*(const float4*)(a0p + ko), *(const float4*)(a0p + ko + 4));
      bf16x8 ah1 = cvt8h(*(const float4*)(a1p + ko), *(const float4*)(a1p + ko + 4));
#pragma unroll
      for (int nt = 0; nt < 4; ++nt) {
        const size_t fo = (((size_t)kt * 16 + w * 4 + nt) * 64 + l) * 8;
        bf16x8 bh = *(const bf16x8*)(bhip + fo);
        bf16x8 bl = *(const bf16x8*)(blop + fo);
        acc[0][nt] = MFMA_BF16(ah0, bh, acc[0][nt], 0, 0, 0);
        acc[0][nt] = MFMA_BF16(ah0, bl, acc[0][nt], 0, 0, 0);
        acc[1][nt] = MFMA_BF16(ah1, bh, acc[1][nt], 0, 0, 0);
        acc[1][nt] = MFMA_BF16(ah1, bl, acc[1][nt], 0, 0, 0);
      }
    }
    __bf16* rdb = (__bf16*)s_rdotb;
#pragma unroll
    for (int mt = 0; mt < 2; ++mt)
#pragma unroll
      for (int nt = 0; nt < 4; ++nt)
#pragma unroll
        for (int r = 0; r < 4; ++r) {
          int m = mt * 16 + lk * 4 + r;
          int n = w * 64 + nt * 16 + lm;
          rdb[m * RSTRIDE + n] = (__bf16)acc[mt][nt][r];
        }
  }
  __syncthreads();

  // --- epilogue: hv in A-frag layout (hi-only), x W3 via MFMA ---
  {
    const int w = t >> 6, l = t & 63, lm = l & 15, lg = l >> 4;
    const ushort* w3h = (const ushort*)(ws + OFF_W3HI);
    const ushort* w3l = (const ushort*)(ws + OFF_W3LO);
    const float2* cw2 = (const float2*)(ws + OFF_CWGP);
    f32x4 accA = {0.f, 0.f, 0.f, 0.f}, accB = {0.f, 0.f, 0.f, 0.f};
#pragma unroll
    for (int mt = 0; mt < 2; ++mt) {
      const int m0 = (w * 2 + mt) * 16;
      const int inst = m0 + lm;
      const int bm = inst >> 5, p = inst & 31;
      const float d = s_d[inst];
      float e0 = 0.f, e1 = 0.f, e2 = 0.f, e3 = 0.f,
            e4 = 0.f, e5 = 0.f, e6 = 0.f, e7 = 0.f;
      float gsum = 0.f, gsq = 0.f;
      int g0 = 0;
      const bool needG = d < DMAX;
      if (needG) {
        g0 = (int)(d * 63.5f + 0.5f) - 4;
        g0 = g0 < 0 ? 0 : (g0 > 120 ? 120 : g0);
#define GEXP(u, ev) { float df = d - (float)(g0 + u) * GDELTA; ev = __expf(GCOEFF * df * df); }
        GEXP(0, e0) GEXP(1, e1) GEXP(2, e2) GEXP(3, e3)
        GEXP(4, e4) GEXP(5, e5) GEXP(6, e6) GEXP(7, e7)
#undef GEXP
        gsum = ((e0 + e1) + (e2 + e3)) + ((e4 + e5) + (e6 + e7));
        gsq = ((e0 * e0 + e1 * e1) + (e2 * e2 + e3 * e3)) +
              ((e4 * e4 + e5 * e5) + (e6 * e6 + e7 * e7));
      }
      const float inv = 1.0f / 274.0f;
      float xsum = ws[OFF_FDSUM + bm] + gsum + d + s_rsum[p];
      float xsq = ws[OFF_FDSQ + bm] + gsq + d * d + s_rsq[p];
      float mu = xsum * inv;
      float var = xsq * inv - mu * mu;
      float rs = rsqrtf(var + 1e-5f);
      float cc = rs * mu;

      f32x4 acc = {0.f, 0.f, 0.f, 0.f};
      const ushort* rrow = s_rdotb + p * RSTRIDE;
      const float* fdo = s_fdop + bm * 256;
      const float2* cwb = cw2 + (size_t)g0 * 128;

#define EPIQ(E, RBITS, F1, F2, HV)                                             \
      {                                                                        \
        float r1 = __uint_as_float((RBITS) << 16);                             \
        float r2 = __uint_as_float((RBITS) & 0xffff0000u);                     \
        float4 tv = *(const float4*)(s_tab4s + T4IDX(qb + (E)));               \
        float2 wv = s_tabw[qb + (E)];                                          \
        float y1 = fmaf(d, wv.x, r1 + (F1));                                   \
        float y2 = fmaf(d, wv.y, r2 + (F2));                                   \
        if (needG) {                                                           \
          const float2* cb = cwb + qb + (E);                                   \
          float2 c;                                                            \
          c = cb[0];   y1 = fmaf(e0, c.x, y1); y2 = fmaf(e0, c.y, y2);         \
          c = cb[128]; y1 = fmaf(e1, c.x, y1); y2 = fmaf(e1, c.y, y2);         \
          c = cb[256]; y1 = fmaf(e2, c.x, y1); y2 = fmaf(e2, c.y, y2);         \
          c = cb[384]; y1 = fmaf(e3, c.x, y1); y2 = fmaf(e3, c.y, y2);         \
          c = cb[512]; y1 = fmaf(e4, c.x, y1); y2 = fmaf(e4, c.y, y2);         \
          c = cb[640]; y1 = fmaf(e5, c.x, y1); y2 = fmaf(e5, c.y, y2);         \
          c = cb[768]; y1 = fmaf(e6, c.x, y1); y2 = fmaf(e6, c.y, y2);         \
          c = cb[896]; y1 = fmaf(e7, c.x, y1); y2 = fmaf(e7, c.y, y2);         \
        }                                                                      \
        float a1 = fmaf(rs, y1, fmaf(-cc, tv.x, tv.z));                        \
        float a2 = fmaf(rs, y2, fmaf(-cc, tv.y, tv.w));                        \
        HV = a1 * a2 * __builtin_amdgcn_rcpf(1.0f + __expf(-a1));              \
      }

#pragma unroll
      for (int kt = 0; kt < 4; ++kt) {
        const int qb = kt * 32 + lg * 8;
        uint4 ra = *(const uint4*)(rrow + 2 * qb);
        uint4 rb = *(const uint4*)(rrow + 2 * qb + 8);
        float4 fA = *(const float4*)(fdo + 2 * qb);
        float4 fB = *(const float4*)(fdo + 2 * qb + 4);
        float4 fC = *(const float4*)(fdo + 2 * qb + 8);
        float4 fD = *(const float4*)(fdo + 2 * qb + 12);
        float hv0, hv1, hv2, hv3, hv4, hv5, hv6, hv7;
        EPIQ(0, ra.x, fA.x, fA.y, hv0)
        EPIQ(1, ra.y, fA.z, fA.w, hv1)
        EPIQ(2, ra.z, fB.x, fB.y, hv2)
        EPIQ(3, ra.w, fB.z, fB.w, hv3)
        EPIQ(4, rb.x, fC.x, fC.y, hv4)
        EPIQ(5, rb.y, fC.z, fC.w, hv5)
        EPIQ(6, rb.z, fD.x, fD.y, hv6)
        EPIQ(7, rb.w, fD.z, fD.w, hv7)
        bf16x8 Ahi = __builtin_bit_cast(
            bf16x8, make_uint4(pk2(hv0, hv1), pk2(hv2, hv3),
                               pk2(hv4, hv5), pk2(hv6, hv7)));
        bf16x8 Bhi = *(const bf16x8*)(w3h + (kt * 64 + l) * 8);
        bf16x8 Blo = *(const bf16x8*)(w3l + (kt * 64 + l) * 8);
        acc = MFMA_BF16(Ahi, Bhi, acc, 0, 0, 0);
        acc = MFMA_BF16(Ahi, Blo, acc, 0, 0, 0);
      }
#undef EPIQ
      if (mt == 0) accA = acc; else accB = acc;
    }

    // Direct C-frag stores: plane = w*16+lm (bm=w, o=lm), rows p=lg*4+0..3
    // (accA) and 16+lg*4+0..3 (accB) are consecutive j -> aligned 16B stores.
    {
      float* ob = out + (((size_t)(w * 16 + lm)) * N + i) * N + j0;
      *(f32x4*)(ob + lg * 4) = accA;
      *(f32x4*)(ob + 16 + lg * 4) = accB;
    }
  }
}

extern "C" void kernel_launch(void* const* d_in, const int* in_sizes, int n_in,
                              void* d_out, int out_size, void* d_ws, size_t ws_size,
                              hipStream_t stream) {
  const float* nf = (const float*)d_in[0];
  const float* rn = (const float*)d_in[1];
  const float* rpe = (const float*)d_in[2];
  const float* ttra = (const float*)d_in[3];
  const float* Wf = (const float*)d_in[4];
  const float* gamma = (const float*)d_in[5];
  const float* beta = (const float*)d_in[6];
  const float* W1 = (const float*)d_in[7];
  const float* W2 = (const float*)d_in[8];
  const float* W3 = (const float*)d_in[9];
  float* out = (float*)d_out;
  float* ws = (float*)d_ws;

  const int BM = in_sizes[0] / 256;       // 4
  const int A = in_sizes[1] / (3 * BM);   // 1536
  const int N = in_sizes[3] / A;          // 384

  k0_all<<<265 + N, 256, 0, stream>>>(nf, Wf, gamma, beta, W1, W2, W3,
                                      ttra, rn, ws, N, A);
  k2_main<<<N * (N / TJ), 256, 0, stream>>>(rpe, ws, out, N);
}

// Round 20
// 190.703 us; speedup vs baseline: 1.3959x; 1.3959x over previous
//
#include <hip/hip_runtime.h>
#include <math.h>

#define ZDIM  128
#define ODIM  16
#define INDIM 274
#define TJ    32
#define GCOEFF (-2016.125f)
#define DMAX  2.25f
#define GDELTA (2.0f / 127.0f)

// workspace layout (float offsets)
#define OFF_TABP  0        // 128*8  {sg1,sg2,sb1,sb2,w144_1,w144_2,0,0}
#define OFF_FDOP  1024     // 4*128*2 paired
#define OFF_W3HI  2048     // 2048 ushort = 1024 floats (W3 B-frag order, hi)
#define OFF_W3LO  3072     // 1024 floats (lo)
#define OFF_FDSUM 4096     // 4
#define OFF_FDSQ  4100     // 4
#define OFF_RR    4104     // 4*N*3 = 4608
#define OFF_BHI   8720     // 32768 ushort (rpe-GEMM B frags hi)
#define OFF_BLO   25104    // 32768 ushort
#define OFF_CWGP  41488    // 128*256 fp32 paired cols [g][2q|2q+1]

#define RSTRIDE 264        // s_rdotb row stride in ushorts (16B-aligned rows)

// s_tab4 de-swizzle: float index 4q + 4*(q>>3) (r13-validated).
#define T4IDX(q) (4 * (q) + 4 * ((q) >> 3))

typedef __attribute__((ext_vector_type(8))) short bf16x8;
typedef __attribute__((ext_vector_type(4))) float f32x4;
#define MFMA_BF16 __builtin_amdgcn_mfma_f32_16x16x32_bf16

static __device__ inline ushort f2bf(float x) {
  union { float f; unsigned u; } v; v.f = x;
  unsigned r = v.u + 0x7fffu + ((v.u >> 16) & 1u);
  return (ushort)(r >> 16);
}
static __device__ inline float bf2f(ushort h) {
  union { unsigned u; float f; } v; v.u = ((unsigned)h) << 16;
  return v.f;
}
// SCRATCH-SPILL CATALOG: (a) local arrays w/ runtime index (r10); (b)
// address-taking of locals (r7); (c) ext-vector element inserts even with
// literal index (r15); (d) register pressure from fused live state (r17);
// (e) aggressive min-waves launch bound forcing VGPR below the body's needs
// (r19: (256,6) -> VGPR 40 -> 346 MB spill writes). Clean: named scalars,
// bit-ops, make_uint4 + bit_cast, bounds that leave the allocator slack.
static __device__ inline unsigned pk2(float a, float b) {
  ushort ua = __builtin_bit_cast(ushort, (__bf16)a);
  ushort ub = __builtin_bit_cast(ushort, (__bf16)b);
  return (unsigned)ua | ((unsigned)ub << 16);
}
static __device__ inline bf16x8 cvt8h(float4 a, float4 b) {
  return __builtin_bit_cast(
      bf16x8, make_uint4(pk2(a.x, a.y), pk2(a.z, a.w),
                         pk2(b.x, b.y), pk2(b.z, b.w)));
}

// Fused preprocessing (unchanged):
__global__ __launch_bounds__(256) void k0_all(
    const float* __restrict__ nf, const float* __restrict__ Wf,
    const float* __restrict__ gamma, const float* __restrict__ beta,
    const float* __restrict__ W1, const float* __restrict__ W2,
    const float* __restrict__ W3, const float* __restrict__ ttra,
    const float* __restrict__ rn, float* __restrict__ ws, int N, int A) {
  const int blk = blockIdx.x;
  const int t = threadIdx.x;

  if (blk < 264) {
    const int flat = blk * 256 + t;
    if (flat < 32768) {
      int e = flat & 7, l = (flat >> 3) & 63, ct = (flat >> 9) & 15, kt = flat >> 13;
      int z = kt * 32 + (l >> 4) * 8 + e;
      int n = ct * 16 + (l & 15);
      int q = n >> 1;
      const float* row = (n & 1) ? (W2 + (size_t)q * INDIM) : (W1 + (size_t)q * INDIM);
      float v = gamma[146 + z] * row[146 + z];
      ushort h = f2bf(v);
      ushort lo = f2bf(v - bf2f(h));
      ((ushort*)(ws + OFF_BHI))[flat] = h;
      ((ushort*)(ws + OFF_BLO))[flat] = lo;
    } else if (flat < 65536) {
      int c = flat - 32768;
      int g = c >> 8, n = c & 255, q = n >> 1;
      const float* row = (n & 1) ? (W2 + (size_t)q * INDIM) : (W1 + (size_t)q * INDIM);
      ws[OFF_CWGP + g * 256 + n] = gamma[16 + g] * row[16 + g];
    } else if (flat < 67584) {
      int f = flat - 65536;  // 0..2047
      int e = f & 7, l = (f >> 3) & 63, kt = (f >> 9) & 3;
      int o = l & 15;
      int q = kt * 32 + (l >> 4) * 8 + e;
      float v = W3[o * 128 + q];
      ushort h = f2bf(v);
      ushort lo = f2bf(v - bf2f(h));
      ((ushort*)(ws + OFF_W3HI))[f] = h;
      ((ushort*)(ws + OFF_W3LO))[f] = lo;
    }
    return;
  }

  if (blk == 264) {
    __shared__ float fd[64];
    if (t < 64) {
      int bm = t >> 4, c = t & 15;
      const float4* a4 = (const float4*)(nf + bm * 256);
      const float4* b4 = (const float4*)(Wf + c * 256);
      float s = 0.f;
      for (int f = 0; f < 64; ++f) {
        float4 a = a4[f], b = b4[f];
        s += a.x * b.x + a.y * b.y + a.z * b.z + a.w * b.w;
      }
      fd[t] = s;
    }
    __syncthreads();
    {
      int q = t & 127, which = t >> 7;
      const float* r = which ? (W2 + (size_t)q * INDIM) : (W1 + (size_t)q * INDIM);
      float sg = 0.f, sb = 0.f;
      for (int c = 0; c < INDIM; ++c) { sg += gamma[c] * r[c]; sb += beta[c] * r[c]; }
      float* tp = ws + OFF_TABP + q * 8;
      tp[0 + which] = sg;
      tp[2 + which] = sb;
      tp[4 + which] = gamma[144] * r[144];
      if (!which) { tp[6] = 0.f; tp[7] = 0.f; }
      for (int bm = 0; bm < 4; ++bm) {
        float f1 = 0.f;
        for (int c = 0; c < 16; ++c) f1 += fd[bm * 16 + c] * gamma[c] * r[c];
        ws[OFF_FDOP + (bm * 128 + q) * 2 + which] = f1;
      }
    }
    if (t < 4) {
      float s = 0.f, q = 0.f;
      for (int c = 0; c < 16; ++c) { float v = fd[t * 16 + c]; s += v; q += v * v; }
      ws[OFF_FDSUM + t] = s;
      ws[OFF_FDSQ + t] = q;
    }
    return;
  }

  // r_repr
  {
    int w = t >> 6, lane = t & 63;
    int flat = (blk - 265) * 4 + w;
    if (flat >= 4 * N) return;
    int bm = flat / N, n = flat - bm * N;
    float a0 = 0.f, a1 = 0.f, a2 = 0.f;
    for (int a = lane; a < A; a += 64) {
      float wv = ttra[(size_t)n * A + a];
      const float* rp = rn + ((size_t)bm * A + a) * 3;
      a0 += wv * rp[0]; a1 += wv * rp[1]; a2 += wv * rp[2];
    }
    for (int s = 32; s; s >>= 1) {
      a0 += __shfl_down(a0, s); a1 += __shfl_down(a1, s); a2 += __shfl_down(a2, s);
    }
    if (lane == 0) {
      float* o = ws + OFF_RR + ((size_t)bm * N + n) * 3;
      o[0] = a0; o[1] = a1; o[2] = a2;
    }
  }
}

// k2: MFMA rdot GEMM (2-product) + MFMA xW3 epilogue (2-product), r18
// structure (direct C-frag stores). Round-20: __launch_bounds__(256,5) —
// VGPR cap 512/5=102 >= the ~64 the body needs (no forced squeeze, unlike
// r19's (256,6) -> 40 VGPR spill storm) while LDS 25088 B permits 5
// resident blocks/CU (occupancy 36.8% -> ~46%).
__global__ __launch_bounds__(256, 5) void k2_main(
    const float* __restrict__ rpe, const float* __restrict__ ws,
    float* __restrict__ out, int N) {
  const int t = threadIdx.x;
  const int njt = N / TJ;
  const int i = blockIdx.x / njt;
  const int j0 = (blockIdx.x % njt) * TJ;

  __shared__ ushort s_rdotb[32 * RSTRIDE];  // 16896 B
  __shared__ float s_tab4s[T4IDX(127) + 4]; // de-swizzled {sg1,sg2,sb1,sb2}
  __shared__ float2 s_tabw[128];            // {w144_1,w144_2}
  __shared__ float s_fdop[1024];            // [bm*256 + 2q + which]
  __shared__ float s_rsum[32], s_rsq[32];
  __shared__ float s_d[128];

  // --- stage tables (read only after the post-GEMM barrier) ---
  if (t < 128) {
    *(float4*)(s_tab4s + T4IDX(t)) = *(const float4*)(ws + OFF_TABP + t * 8);
    s_tabw[t] = *(const float2*)(ws + OFF_TABP + t * 8 + 4);
  }
  for (int idx = t; idx < 1024; idx += 256) s_fdop[idx] = ws[OFF_FDOP + idx];

  // --- distances ---
  if (t < 128) {
    int bm = t >> 5, p = t & 31;
    const float* rr = ws + OFF_RR;
    const float* ri = rr + ((size_t)bm * N + i) * 3;
    const float* rj = rr + ((size_t)bm * N + j0 + p) * 3;
    float dx = ri[0] - rj[0], dy = ri[1] - rj[1], dz = ri[2] - rj[2];
    float sq = dx * dx + dy * dy + dz * dz;
    s_d[t] = sq > 0.f ? sqrtf(sq) : 0.f;
  }
  // --- rpe row sums (4 threads per row) ---
  if (t < 128) {
    int p = t >> 2, seg = t & 3;
    const float* row = rpe + ((size_t)(i * N) + j0 + p) * ZDIM + seg * 32;
    float s = 0.f, q = 0.f;
    for (int u = 0; u < 32; u += 4) {
      float4 v = *(const float4*)(row + u);
      s += v.x + v.y + v.z + v.w;
      q += v.x * v.x + v.y * v.y + v.z * v.z + v.w * v.w;
    }
    s += __shfl_xor(s, 1); q += __shfl_xor(q, 1);
    s += __shfl_xor(s, 2); q += __shfl_xor(q, 2);
    if (seg == 0) { s_rsum[p] = s; s_rsq[p] = q; }
  }

  // --- MFMA GEMM: rdot[32 rows][256 paired cols], 2-product split ---
  {
    const int w = t >> 6, l = t & 63, lm = l & 15, lk = l >> 4;
    f32x4 acc[2][4];
#pragma unroll
    for (int mt = 0; mt < 2; ++mt)
#pragma unroll
      for (int nt = 0; nt < 4; ++nt) acc[mt][nt] = (f32x4){0.f, 0.f, 0.f, 0.f};
    const float* a0p = rpe + ((size_t)(i * N) + j0 + lm) * ZDIM;
    const float* a1p = a0p + 16 * ZDIM;
    const ushort* bhip = (const ushort*)(ws + OFF_BHI);
    const ushort* blop = (const ushort*)(ws + OFF_BLO);
#pragma unroll
    for (int kt = 0; kt < 4; ++kt) {
      const int ko = kt * 32 + lk * 8;
      bf16x8 ah0 = cvt8h(*(const float4*)(a0p + ko), *(const float4*)(a0p + ko + 4));
      bf16x8 ah1 = cvt8h(*(const float4*)(a1p + ko), *(const float4*)(a1p + ko + 4));
#pragma unroll
      for (int nt = 0; nt < 4; ++nt) {
        const size_t fo = (((size_t)kt * 16 + w * 4 + nt) * 64 + l) * 8;
        bf16x8 bh = *(const bf16x8*)(bhip + fo);
        bf16x8 bl = *(const bf16x8*)(blop + fo);
        acc[0][nt] = MFMA_BF16(ah0, bh, acc[0][nt], 0, 0, 0);
        acc[0][nt] = MFMA_BF16(ah0, bl, acc[0][nt], 0, 0, 0);
        acc[1][nt] = MFMA_BF16(ah1, bh, acc[1][nt], 0, 0, 0);
        acc[1][nt] = MFMA_BF16(ah1, bl, acc[1][nt], 0, 0, 0);
      }
    }
    __bf16* rdb = (__bf16*)s_rdotb;
#pragma unroll
    for (int mt = 0; mt < 2; ++mt)
#pragma unroll
      for (int nt = 0; nt < 4; ++nt)
#pragma unroll
        for (int r = 0; r < 4; ++r) {
          int m = mt * 16 + lk * 4 + r;
          int n = w * 64 + nt * 16 + lm;
          rdb[m * RSTRIDE + n] = (__bf16)acc[mt][nt][r];
        }
  }
  __syncthreads();

  // --- epilogue: hv in A-frag layout (hi-only), x W3 via MFMA ---
  {
    const int w = t >> 6, l = t & 63, lm = l & 15, lg = l >> 4;
    const ushort* w3h = (const ushort*)(ws + OFF_W3HI);
    const ushort* w3l = (const ushort*)(ws + OFF_W3LO);
    const float2* cw2 = (const float2*)(ws + OFF_CWGP);
    f32x4 accA = {0.f, 0.f, 0.f, 0.f}, accB = {0.f, 0.f, 0.f, 0.f};
#pragma unroll
    for (int mt = 0; mt < 2; ++mt) {
      const int m0 = (w * 2 + mt) * 16;
      const int inst = m0 + lm;
      const int bm = inst >> 5, p = inst & 31;
      const float d = s_d[inst];
      float e0 = 0.f, e1 = 0.f, e2 = 0.f, e3 = 0.f,
            e4 = 0.f, e5 = 0.f, e6 = 0.f, e7 = 0.f;
      float gsum = 0.f, gsq = 0.f;
      int g0 = 0;
      const bool needG = d < DMAX;
      if (needG) {
        g0 = (int)(d * 63.5f + 0.5f) - 4;
        g0 = g0 < 0 ? 0 : (g0 > 120 ? 120 : g0);
#define GEXP(u, ev) { float df = d - (float)(g0 + u) * GDELTA; ev = __expf(GCOEFF * df * df); }
        GEXP(0, e0) GEXP(1, e1) GEXP(2, e2) GEXP(3, e3)
        GEXP(4, e4) GEXP(5, e5) GEXP(6, e6) GEXP(7, e7)
#undef GEXP
        gsum = ((e0 + e1) + (e2 + e3)) + ((e4 + e5) + (e6 + e7));
        gsq = ((e0 * e0 + e1 * e1) + (e2 * e2 + e3 * e3)) +
              ((e4 * e4 + e5 * e5) + (e6 * e6 + e7 * e7));
      }
      const float inv = 1.0f / 274.0f;
      float xsum = ws[OFF_FDSUM + bm] + gsum + d + s_rsum[p];
      float xsq = ws[OFF_FDSQ + bm] + gsq + d * d + s_rsq[p];
      float mu = xsum * inv;
      float var = xsq * inv - mu * mu;
      float rs = rsqrtf(var + 1e-5f);
      float cc = rs * mu;

      f32x4 acc = {0.f, 0.f, 0.f, 0.f};
      const ushort* rrow = s_rdotb + p * RSTRIDE;
      const float* fdo = s_fdop + bm * 256;
      const float2* cwb = cw2 + (size_t)g0 * 128;

#define EPIQ(E, RBITS, F1, F2, HV)                                             \
      {                                                                        \
        float r1 = __uint_as_float((RBITS) << 16);                             \
        float r2 = __uint_as_float((RBITS) & 0xffff0000u);                     \
        float4 tv = *(const float4*)(s_tab4s + T4IDX(qb + (E)));               \
        float2 wv = s_tabw[qb + (E)];                                          \
        float y1 = fmaf(d, wv.x, r1 + (F1));                                   \
        float y2 = fmaf(d, wv.y, r2 + (F2));                                   \
        if (needG) {                                                           \
          const float2* cb = cwb + qb + (E);                                   \
          float2 c;                                                            \
          c = cb[0];   y1 = fmaf(e0, c.x, y1); y2 = fmaf(e0, c.y, y2);         \
          c = cb[128]; y1 = fmaf(e1, c.x, y1); y2 = fmaf(e1, c.y, y2);         \
          c = cb[256]; y1 = fmaf(e2, c.x, y1); y2 = fmaf(e2, c.y, y2);         \
          c = cb[384]; y1 = fmaf(e3, c.x, y1); y2 = fmaf(e3, c.y, y2);         \
          c = cb[512]; y1 = fmaf(e4, c.x, y1); y2 = fmaf(e4, c.y, y2);         \
          c = cb[640]; y1 = fmaf(e5, c.x, y1); y2 = fmaf(e5, c.y, y2);         \
          c = cb[768]; y1 = fmaf(e6, c.x, y1); y2 = fmaf(e6, c.y, y2);         \
          c = cb[896]; y1 = fmaf(e7, c.x, y1); y2 = fmaf(e7, c.y, y2);         \
        }                                                                      \
        float a1 = fmaf(rs, y1, fmaf(-cc, tv.x, tv.z));                        \
        float a2 = fmaf(rs, y2, fmaf(-cc, tv.y, tv.w));                        \
        HV = a1 * a2 * __builtin_amdgcn_rcpf(1.0f + __expf(-a1));              \
      }

#pragma unroll
      for (int kt = 0; kt < 4; ++kt) {
        const int qb = kt * 32 + lg * 8;
        uint4 ra = *(const uint4*)(rrow + 2 * qb);
        uint4 rb = *(const uint4*)(rrow + 2 * qb + 8);
        float4 fA = *(const float4*)(fdo + 2 * qb);
        float4 fB = *(const float4*)(fdo + 2 * qb + 4);
        float4 fC = *(const float4*)(fdo + 2 * qb + 8);
        float4 fD = *(const float4*)(fdo + 2 * qb + 12);
        float hv0, hv1, hv2, hv3, hv4, hv5, hv6, hv7;
        EPIQ(0, ra.x, fA.x, fA.y, hv0)
        EPIQ(1, ra.y, fA.z, fA.w, hv1)
        EPIQ(2, ra.z, fB.x, fB.y, hv2)
        EPIQ(3, ra.w, fB.z, fB.w, hv3)
        EPIQ(4, rb.x, fC.x, fC.y, hv4)
        EPIQ(5, rb.y, fC.z, fC.w, hv5)
        EPIQ(6, rb.z, fD.x, fD.y, hv6)
        EPIQ(7, rb.w, fD.z, fD.w, hv7)
        bf16x8 Ahi = __builtin_bit_cast(
            bf16x8, make_uint4(pk2(hv0, hv1), pk2(hv2, hv3),
                               pk2(hv4, hv5), pk2(hv6, hv7)));
        bf16x8 Bhi = *(const bf16x8*)(w3h + (kt * 64 + l) * 8);
        bf16x8 Blo = *(const bf16x8*)(w3l + (kt * 64 + l) * 8);
        acc = MFMA_BF16(Ahi, Bhi, acc, 0, 0, 0);
        acc = MFMA_BF16(Ahi, Blo, acc, 0, 0, 0);
      }
#undef EPIQ
      if (mt == 0) accA = acc; else accB = acc;
    }

    // Direct C-frag stores: plane = w*16+lm (bm=w, o=lm), rows p=lg*4+0..3
    // (accA) and 16+lg*4+0..3 (accB) are consecutive j -> aligned 16B stores.
    {
      float* ob = out + (((size_t)(w * 16 + lm)) * N + i) * N + j0;
      *(f32x4*)(ob + lg * 4) = accA;
      *(f32x4*)(ob + 16 + lg * 4) = accB;
    }
  }
}

extern "C" void kernel_launch(void* const* d_in, const int* in_sizes, int n_in,
                              void* d_out, int out_size, void* d_ws, size_t ws_size,
                              hipStream_t stream) {
  const float* nf = (const float*)d_in[0];
  const float* rn = (const float*)d_in[1];
  const float* rpe = (const float*)d_in[2];
  const float* ttra = (const float*)d_in[3];
  const float* Wf = (const float*)d_in[4];
  const float* gamma = (const float*)d_in[5];
  const float* beta = (const float*)d_in[6];
  const float* W1 = (const float*)d_in[7];
  const float* W2 = (const float*)d_in[8];
  const float* W3 = (const float*)d_in[9];
  float* out = (float*)d_out;
  float* ws = (float*)d_ws;

  const int BM = in_sizes[0] / 256;       // 4
  const int A = in_sizes[1] / (3 * BM);   // 1536
  const int N = in_sizes[3] / A;          // 384

  k0_all<<<265 + N, 256, 0, stream>>>(nf, Wf, gamma, beta, W1, W2, W3,
                                      ttra, rn, ws, N, A);
  k2_main<<<N * (N / TJ), 256, 0, stream>>>(rpe, ws, out, N);
}

// Round 21
// 153.775 us; speedup vs baseline: 1.7311x; 1.2401x over previous
//
#include <hip/hip_runtime.h>
#include <math.h>

#define ZDIM  128
#define ODIM  16
#define INDIM 274
#define TJ    32
#define GCOEFF (-2016.125f)
#define DMAX  2.25f
#define GDELTA (2.0f / 127.0f)

// workspace layout (float offsets)
#define OFF_TABP  0        // 128*8  {sg1,sg2,sb1,sb2,w144_1,w144_2,0,0}
#define OFF_FDOP  1024     // 4*128*2 paired
#define OFF_W3HI  2048     // 2048 ushort = 1024 floats (W3 B-frag order, hi)
#define OFF_W3LO  3072     // 1024 floats (lo)
#define OFF_FDSUM 4096     // 4
#define OFF_FDSQ  4100     // 4
#define OFF_RR    4104     // 4*N*3 = 4608
#define OFF_BHI   8720     // 32768 ushort (rpe-GEMM B frags hi)
#define OFF_BLO   25104    // 32768 ushort
#define OFF_CWGP  41488    // 128*256 fp32 paired cols [g][2q|2q+1]

#define RSTRIDE 264        // s_rdotb row stride in ushorts (16B-aligned rows)

// s_tab4 de-swizzle: float index 4q + 4*(q>>3) (r13-validated).
#define T4IDX(q) (4 * (q) + 4 * ((q) >> 3))

typedef __attribute__((ext_vector_type(8))) short bf16x8;
typedef __attribute__((ext_vector_type(4))) float f32x4;
#define MFMA_BF16 __builtin_amdgcn_mfma_f32_16x16x32_bf16

static __device__ inline ushort f2bf(float x) {
  union { float f; unsigned u; } v; v.f = x;
  unsigned r = v.u + 0x7fffu + ((v.u >> 16) & 1u);
  return (ushort)(r >> 16);
}
static __device__ inline float bf2f(ushort h) {
  union { unsigned u; float f; } v; v.u = ((unsigned)h) << 16;
  return v.f;
}
// SCRATCH-SPILL CATALOG (final): (a) local arrays w/ runtime index (r10);
// (b) address-taking of locals (r7); (c) ext-vector element inserts even
// with literal index (r15); (d) register pressure from fused live state
// (r17); (e) ANY __launch_bounds__ min-waves above the natural allocation
// — (256,5) squeezed VGPR 64->48 (r20), (256,6) -> 40 (r19), both spill
// storms. Clean: named scalars, bit-ops, make_uint4 + bit_cast, (256,4).
static __device__ inline unsigned pk2(float a, float b) {
  ushort ua = __builtin_bit_cast(ushort, (__bf16)a);
  ushort ub = __builtin_bit_cast(ushort, (__bf16)b);
  return (unsigned)ua | ((unsigned)ub << 16);
}
static __device__ inline bf16x8 cvt8h(float4 a, float4 b) {
  return __builtin_bit_cast(
      bf16x8, make_uint4(pk2(a.x, a.y), pk2(a.z, a.w),
                         pk2(b.x, b.y), pk2(b.z, b.w)));
}

// Fused preprocessing:
//  blocks 0..263  : fills (rpe-GEMM bf16 hi/lo, cwg paired, W3 frags)
//  block  264     : scalar tables (fd, sg/sb, fdop, fdsum)
//  blocks 265..   : r_repr (one wave per (bm,n))
__global__ __launch_bounds__(256) void k0_all(
    const float* __restrict__ nf, const float* __restrict__ Wf,
    const float* __restrict__ gamma, const float* __restrict__ beta,
    const float* __restrict__ W1, const float* __restrict__ W2,
    const float* __restrict__ W3, const float* __restrict__ ttra,
    const float* __restrict__ rn, float* __restrict__ ws, int N, int A) {
  const int blk = blockIdx.x;
  const int t = threadIdx.x;

  if (blk < 264) {
    const int flat = blk * 256 + t;
    if (flat < 32768) {
      int e = flat & 7, l = (flat >> 3) & 63, ct = (flat >> 9) & 15, kt = flat >> 13;
      int z = kt * 32 + (l >> 4) * 8 + e;
      int n = ct * 16 + (l & 15);
      int q = n >> 1;
      const float* row = (n & 1) ? (W2 + (size_t)q * INDIM) : (W1 + (size_t)q * INDIM);
      float v = gamma[146 + z] * row[146 + z];
      ushort h = f2bf(v);
      ushort lo = f2bf(v - bf2f(h));
      ((ushort*)(ws + OFF_BHI))[flat] = h;
      ((ushort*)(ws + OFF_BLO))[flat] = lo;
    } else if (flat < 65536) {
      int c = flat - 32768;
      int g = c >> 8, n = c & 255, q = n >> 1;
      const float* row = (n & 1) ? (W2 + (size_t)q * INDIM) : (W1 + (size_t)q * INDIM);
      ws[OFF_CWGP + g * 256 + n] = gamma[16 + g] * row[16 + g];
    } else if (flat < 67584) {
      int f = flat - 65536;  // 0..2047
      int e = f & 7, l = (f >> 3) & 63, kt = (f >> 9) & 3;
      int o = l & 15;
      int q = kt * 32 + (l >> 4) * 8 + e;
      float v = W3[o * 128 + q];
      ushort h = f2bf(v);
      ushort lo = f2bf(v - bf2f(h));
      ((ushort*)(ws + OFF_W3HI))[f] = h;
      ((ushort*)(ws + OFF_W3LO))[f] = lo;
    }
    return;
  }

  if (blk == 264) {
    __shared__ float fd[64];
    if (t < 64) {
      int bm = t >> 4, c = t & 15;
      const float4* a4 = (const float4*)(nf + bm * 256);
      const float4* b4 = (const float4*)(Wf + c * 256);
      float s = 0.f;
      for (int f = 0; f < 64; ++f) {
        float4 a = a4[f], b = b4[f];
        s += a.x * b.x + a.y * b.y + a.z * b.z + a.w * b.w;
      }
      fd[t] = s;
    }
    __syncthreads();
    {
      int q = t & 127, which = t >> 7;
      const float* r = which ? (W2 + (size_t)q * INDIM) : (W1 + (size_t)q * INDIM);
      float sg = 0.f, sb = 0.f;
      for (int c = 0; c < INDIM; ++c) { sg += gamma[c] * r[c]; sb += beta[c] * r[c]; }
      float* tp = ws + OFF_TABP + q * 8;
      tp[0 + which] = sg;
      tp[2 + which] = sb;
      tp[4 + which] = gamma[144] * r[144];
      if (!which) { tp[6] = 0.f; tp[7] = 0.f; }
      for (int bm = 0; bm < 4; ++bm) {
        float f1 = 0.f;
        for (int c = 0; c < 16; ++c) f1 += fd[bm * 16 + c] * gamma[c] * r[c];
        ws[OFF_FDOP + (bm * 128 + q) * 2 + which] = f1;
      }
    }
    if (t < 4) {
      float s = 0.f, q = 0.f;
      for (int c = 0; c < 16; ++c) { float v = fd[t * 16 + c]; s += v; q += v * v; }
      ws[OFF_FDSUM + t] = s;
      ws[OFF_FDSQ + t] = q;
    }
    return;
  }

  // r_repr
  {
    int w = t >> 6, lane = t & 63;
    int flat = (blk - 265) * 4 + w;
    if (flat >= 4 * N) return;
    int bm = flat / N, n = flat - bm * N;
    float a0 = 0.f, a1 = 0.f, a2 = 0.f;
    for (int a = lane; a < A; a += 64) {
      float wv = ttra[(size_t)n * A + a];
      const float* rp = rn + ((size_t)bm * A + a) * 3;
      a0 += wv * rp[0]; a1 += wv * rp[1]; a2 += wv * rp[2];
    }
    for (int s = 32; s; s >>= 1) {
      a0 += __shfl_down(a0, s); a1 += __shfl_down(a1, s); a2 += __shfl_down(a2, s);
    }
    if (lane == 0) {
      float* o = ws + OFF_RR + ((size_t)bm * N + n) * 3;
      o[0] = a0; o[1] = a1; o[2] = a2;
    }
  }
}

// k2: MFMA rdot GEMM (2-product) + MFMA xW3 epilogue (2-product), direct
// C-frag stores. FINAL = r18 config: (256,4) is the only non-spilling
// launch bound (catalog entry (e)). 710 -> 154.5 us over the session.
__global__ __launch_bounds__(256, 4) void k2_main(
    const float* __restrict__ rpe, const float* __restrict__ ws,
    float* __restrict__ out, int N) {
  const int t = threadIdx.x;
  const int njt = N / TJ;
  const int i = blockIdx.x / njt;
  const int j0 = (blockIdx.x % njt) * TJ;

  __shared__ ushort s_rdotb[32 * RSTRIDE];  // 16896 B
  __shared__ float s_tab4s[T4IDX(127) + 4]; // de-swizzled {sg1,sg2,sb1,sb2}
  __shared__ float2 s_tabw[128];            // {w144_1,w144_2}
  __shared__ float s_fdop[1024];            // [bm*256 + 2q + which]
  __shared__ float s_rsum[32], s_rsq[32];
  __shared__ float s_d[128];

  // --- stage tables (read only after the post-GEMM barrier) ---
  if (t < 128) {
    *(float4*)(s_tab4s + T4IDX(t)) = *(const float4*)(ws + OFF_TABP + t * 8);
    s_tabw[t] = *(const float2*)(ws + OFF_TABP + t * 8 + 4);
  }
  for (int idx = t; idx < 1024; idx += 256) s_fdop[idx] = ws[OFF_FDOP + idx];

  // --- distances ---
  if (t < 128) {
    int bm = t >> 5, p = t & 31;
    const float* rr = ws + OFF_RR;
    const float* ri = rr + ((size_t)bm * N + i) * 3;
    const float* rj = rr + ((size_t)bm * N + j0 + p) * 3;
    float dx = ri[0] - rj[0], dy = ri[1] - rj[1], dz = ri[2] - rj[2];
    float sq = dx * dx + dy * dy + dz * dz;
    s_d[t] = sq > 0.f ? sqrtf(sq) : 0.f;
  }
  // --- rpe row sums (4 threads per row) ---
  if (t < 128) {
    int p = t >> 2, seg = t & 3;
    const float* row = rpe + ((size_t)(i * N) + j0 + p) * ZDIM + seg * 32;
    float s = 0.f, q = 0.f;
    for (int u = 0; u < 32; u += 4) {
      float4 v = *(const float4*)(row + u);
      s += v.x + v.y + v.z + v.w;
      q += v.x * v.x + v.y * v.y + v.z * v.z + v.w * v.w;
    }
    s += __shfl_xor(s, 1); q += __shfl_xor(q, 1);
    s += __shfl_xor(s, 2); q += __shfl_xor(q, 2);
    if (seg == 0) { s_rsum[p] = s; s_rsq[p] = q; }
  }

  // --- MFMA GEMM: rdot[32 rows][256 paired cols], 2-product split ---
  {
    const int w = t >> 6, l = t & 63, lm = l & 15, lk = l >> 4;
    f32x4 acc[2][4];
#pragma unroll
    for (int mt = 0; mt < 2; ++mt)
#pragma unroll
      for (int nt = 0; nt < 4; ++nt) acc[mt][nt] = (f32x4){0.f, 0.f, 0.f, 0.f};
    const float* a0p = rpe + ((size_t)(i * N) + j0 + lm) * ZDIM;
    const float* a1p = a0p + 16 * ZDIM;
    const ushort* bhip = (const ushort*)(ws + OFF_BHI);
    const ushort* blop = (const ushort*)(ws + OFF_BLO);
#pragma unroll
    for (int kt = 0; kt < 4; ++kt) {
      const int ko = kt * 32 + lk * 8;
      bf16x8 ah0 = cvt8h(*(const float4*)(a0p + ko), *(const float4*)(a0p + ko + 4));
      bf16x8 ah1 = cvt8h(*(const float4*)(a1p + ko), *(const float4*)(a1p + ko + 4));
#pragma unroll
      for (int nt = 0; nt < 4; ++nt) {
        const size_t fo = (((size_t)kt * 16 + w * 4 + nt) * 64 + l) * 8;
        bf16x8 bh = *(const bf16x8*)(bhip + fo);
        bf16x8 bl = *(const bf16x8*)(blop + fo);
        acc[0][nt] = MFMA_BF16(ah0, bh, acc[0][nt], 0, 0, 0);
        acc[0][nt] = MFMA_BF16(ah0, bl, acc[0][nt], 0, 0, 0);
        acc[1][nt] = MFMA_BF16(ah1, bh, acc[1][nt], 0, 0, 0);
        acc[1][nt] = MFMA_BF16(ah1, bl, acc[1][nt], 0, 0, 0);
      }
    }
    __bf16* rdb = (__bf16*)s_rdotb;
#pragma unroll
    for (int mt = 0; mt < 2; ++mt)
#pragma unroll
      for (int nt = 0; nt < 4; ++nt)
#pragma unroll
        for (int r = 0; r < 4; ++r) {
          int m = mt * 16 + lk * 4 + r;
          int n = w * 64 + nt * 16 + lm;
          rdb[m * RSTRIDE + n] = (__bf16)acc[mt][nt][r];
        }
  }
  __syncthreads();

  // --- epilogue: hv in A-frag layout (hi-only), x W3 via MFMA ---
  {
    const int w = t >> 6, l = t & 63, lm = l & 15, lg = l >> 4;
    const ushort* w3h = (const ushort*)(ws + OFF_W3HI);
    const ushort* w3l = (const ushort*)(ws + OFF_W3LO);
    const float2* cw2 = (const float2*)(ws + OFF_CWGP);
    f32x4 accA = {0.f, 0.f, 0.f, 0.f}, accB = {0.f, 0.f, 0.f, 0.f};
#pragma unroll
    for (int mt = 0; mt < 2; ++mt) {
      const int m0 = (w * 2 + mt) * 16;
      const int inst = m0 + lm;
      const int bm = inst >> 5, p = inst & 31;
      const float d = s_d[inst];
      float e0 = 0.f, e1 = 0.f, e2 = 0.f, e3 = 0.f,
            e4 = 0.f, e5 = 0.f, e6 = 0.f, e7 = 0.f;
      float gsum = 0.f, gsq = 0.f;
      int g0 = 0;
      const bool needG = d < DMAX;
      if (needG) {
        g0 = (int)(d * 63.5f + 0.5f) - 4;
        g0 = g0 < 0 ? 0 : (g0 > 120 ? 120 : g0);
#define GEXP(u, ev) { float df = d - (float)(g0 + u) * GDELTA; ev = __expf(GCOEFF * df * df); }
        GEXP(0, e0) GEXP(1, e1) GEXP(2, e2) GEXP(3, e3)
        GEXP(4, e4) GEXP(5, e5) GEXP(6, e6) GEXP(7, e7)
#undef GEXP
        gsum = ((e0 + e1) + (e2 + e3)) + ((e4 + e5) + (e6 + e7));
        gsq = ((e0 * e0 + e1 * e1) + (e2 * e2 + e3 * e3)) +
              ((e4 * e4 + e5 * e5) + (e6 * e6 + e7 * e7));
      }
      const float inv = 1.0f / 274.0f;
      float xsum = ws[OFF_FDSUM + bm] + gsum + d + s_rsum[p];
      float xsq = ws[OFF_FDSQ + bm] + gsq + d * d + s_rsq[p];
      float mu = xsum * inv;
      float var = xsq * inv - mu * mu;
      float rs = rsqrtf(var + 1e-5f);
      float cc = rs * mu;

      f32x4 acc = {0.f, 0.f, 0.f, 0.f};
      const ushort* rrow = s_rdotb + p * RSTRIDE;
      const float* fdo = s_fdop + bm * 256;
      const float2* cwb = cw2 + (size_t)g0 * 128;

#define EPIQ(E, RBITS, F1, F2, HV)                                             \
      {                                                                        \
        float r1 = __uint_as_float((RBITS) << 16);                             \
        float r2 = __uint_as_float((RBITS) & 0xffff0000u);                     \
        float4 tv = *(const float4*)(s_tab4s + T4IDX(qb + (E)));               \
        float2 wv = s_tabw[qb + (E)];                                          \
        float y1 = fmaf(d, wv.x, r1 + (F1));                                   \
        float y2 = fmaf(d, wv.y, r2 + (F2));                                   \
        if (needG) {                                                           \
          const float2* cb = cwb + qb + (E);                                   \
          float2 c;                                                            \
          c = cb[0];   y1 = fmaf(e0, c.x, y1); y2 = fmaf(e0, c.y, y2);         \
          c = cb[128]; y1 = fmaf(e1, c.x, y1); y2 = fmaf(e1, c.y, y2);         \
          c = cb[256]; y1 = fmaf(e2, c.x, y1); y2 = fmaf(e2, c.y, y2);         \
          c = cb[384]; y1 = fmaf(e3, c.x, y1); y2 = fmaf(e3, c.y, y2);         \
          c = cb[512]; y1 = fmaf(e4, c.x, y1); y2 = fmaf(e4, c.y, y2);         \
          c = cb[640]; y1 = fmaf(e5, c.x, y1); y2 = fmaf(e5, c.y, y2);         \
          c = cb[768]; y1 = fmaf(e6, c.x, y1); y2 = fmaf(e6, c.y, y2);         \
          c = cb[896]; y1 = fmaf(e7, c.x, y1); y2 = fmaf(e7, c.y, y2);         \
        }                                                                      \
        float a1 = fmaf(rs, y1, fmaf(-cc, tv.x, tv.z));                        \
        float a2 = fmaf(rs, y2, fmaf(-cc, tv.y, tv.w));                        \
        HV = a1 * a2 * __builtin_amdgcn_rcpf(1.0f + __expf(-a1));              \
      }

#pragma unroll
      for (int kt = 0; kt < 4; ++kt) {
        const int qb = kt * 32 + lg * 8;
        uint4 ra = *(const uint4*)(rrow + 2 * qb);
        uint4 rb = *(const uint4*)(rrow + 2 * qb + 8);
        float4 fA = *(const float4*)(fdo + 2 * qb);
        float4 fB = *(const float4*)(fdo + 2 * qb + 4);
        float4 fC = *(const float4*)(fdo + 2 * qb + 8);
        float4 fD = *(const float4*)(fdo + 2 * qb + 12);
        float hv0, hv1, hv2, hv3, hv4, hv5, hv6, hv7;
        EPIQ(0, ra.x, fA.x, fA.y, hv0)
        EPIQ(1, ra.y, fA.z, fA.w, hv1)
        EPIQ(2, ra.z, fB.x, fB.y, hv2)
        EPIQ(3, ra.w, fB.z, fB.w, hv3)
        EPIQ(4, rb.x, fC.x, fC.y, hv4)
        EPIQ(5, rb.y, fC.z, fC.w, hv5)
        EPIQ(6, rb.z, fD.x, fD.y, hv6)
        EPIQ(7, rb.w, fD.z, fD.w, hv7)
        bf16x8 Ahi = __builtin_bit_cast(
            bf16x8, make_uint4(pk2(hv0, hv1), pk2(hv2, hv3),
                               pk2(hv4, hv5), pk2(hv6, hv7)));
        bf16x8 Bhi = *(const bf16x8*)(w3h + (kt * 64 + l) * 8);
        bf16x8 Blo = *(const bf16x8*)(w3l + (kt * 64 + l) * 8);
        acc = MFMA_BF16(Ahi, Bhi, acc, 0, 0, 0);
        acc = MFMA_BF16(Ahi, Blo, acc, 0, 0, 0);
      }
#undef EPIQ
      if (mt == 0) accA = acc; else accB = acc;
    }

    // Direct C-frag stores: plane = w*16+lm (bm=w, o=lm), rows p=lg*4+0..3
    // (accA) and 16+lg*4+0..3 (accB) are consecutive j -> aligned 16B stores.
    {
      float* ob = out + (((size_t)(w * 16 + lm)) * N + i) * N + j0;
      *(f32x4*)(ob + lg * 4) = accA;
      *(f32x4*)(ob + 16 + lg * 4) = accB;
    }
  }
}

extern "C" void kernel_launch(void* const* d_in, const int* in_sizes, int n_in,
                              void* d_out, int out_size, void* d_ws, size_t ws_size,
                              hipStream_t stream) {
  const float* nf = (const float*)d_in[0];
  const float* rn = (const float*)d_in[1];
  const float* rpe = (const float*)d_in[2];
  const float* ttra = (const float*)d_in[3];
  const float* Wf = (const float*)d_in[4];
  const float* gamma = (const float*)d_in[5];
  const float* beta = (const float*)d_in[6];
  const float* W1 = (const float*)d_in[7];
  const float* W2 = (const float*)d_in[8];
  const float* W3 = (const float*)d_in[9];
  float* out = (float*)d_out;
  float* ws = (float*)d_ws;

  const int BM = in_sizes[0] / 256;       // 4
  const int A = in_sizes[1] / (3 * BM);   // 1536
  const int N = in_sizes[3] / A;          // 384

  k0_all<<<265 + N, 256, 0, stream>>>(nf, Wf, gamma, beta, W1, W2, W3,
                                      ttra, rn, ws, N, A);
  k2_main<<<N * (N / TJ), 256, 0, stream>>>(rpe, ws, out, N);
}